// Round 7
// baseline (376.073 us; speedup 1.0000x reference)
//
#include <hip/hip_runtime.h>
#include <hip/hip_bf16.h>

// Problem constants (from setup_inputs): N=8192 points, k=8.
#define NPTS 8192
#define KNN 8
#define SEGS 64                // candidate segments per point -> 32 waves/CU
#define PPB 8                  // points per block
#define BLK (SEGS * PPB)       // 512 threads, 8 waves
#define SEGLEN (NPTS / SEGS)   // 128 candidates per segment
#define NSAMP 8                // threshold samples per thread (512 per point)
#define NWORDS (SEGLEN / 32)   // 4 bitmask words per thread
// grid = NPTS/PPB = 1024 blocks -> 4 blocks/CU * 8 waves = 32 waves/CU (HW max)

// Pack (x,y,z,|p|^2) and zero the output accumulator.
__global__ __launch_bounds__(256) void prep_kernel(const float* __restrict__ means,
                                                   float4* __restrict__ pts,
                                                   float* __restrict__ out) {
    int i = blockIdx.x * 256 + threadIdx.x;
    if (i == 0 && blockIdx.x == 0) out[0] = 0.0f;
    if (i < NPTS) {
        float x = means[3 * i + 0];
        float y = means[3 * i + 1];
        float z = means[3 * i + 2];
        pts[i] = make_float4(x, y, z, x * x + y * y + z * z);
    }
}

// Exact kNN via sample-threshold filter with register-bitmask survivors:
//  A) 512 sampled candidates/point -> T = 8th-smallest sampled key (upper bound
//     on the true 8th key, since the sample is a subset).
//  B) full scan; keep-bit per candidate: m = m+m+keep (v_cmp + v_addc, 2 ops).
//     7 VALU/candidate total; no LDS traffic, no capacity limit.
//  C) decode set bits (~2/thread), recompute exact f32 d2, insert-8 + tree merge.
// Keys pack (d2 top 19 bits | 13-bit idx): unique, total order, jax tie-break.
__global__ __launch_bounds__(BLK, 8) void knn_kernel(const float4* __restrict__ pts,
                                                     const float* __restrict__ normals,
                                                     float* __restrict__ out) {
    __shared__ unsigned int lds_keys[SEGS][PPB][KNN + 1];  // merge scratch (+1 pad)
    __shared__ unsigned int lds_T[PPB];
    __shared__ int lds_nbr[PPB][KNN];
    __shared__ float lds_red[BLK / 64];

    const int tid = threadIdx.x;
    const int pl = tid & (PPB - 1);   // point within block
    const int seg = tid >> 3;         // segment (PPB==8)
    const int i = blockIdx.x * PPB + pl;

    const float4 mp = pts[i];
    const float mx2 = -2.0f * mp.x;
    const float my2 = -2.0f * mp.y;
    const float mz2 = -2.0f * mp.z;
    const int j0 = seg * SEGLEN;

    unsigned int best[KNN];
#pragma unroll
    for (int s = 0; s < KNN; ++s) best[s] = 0xFFFFFFFFu;

    // ---- Phase A: sampled scan with full insert (8 samples, stride 16) ----
#pragma unroll
    for (int s8 = 0; s8 < NSAMP; ++s8) {
        const int j = j0 + s8 * (SEGLEN / NSAMP);
        const float4 q = pts[j];
        const float d2 = fmaxf(fmaf(mx2, q.x, fmaf(my2, q.y, fmaf(mz2, q.z, mp.w + q.w))), 0.0f);
        unsigned int key = (__float_as_uint(d2) & 0xFFFFE000u) | (unsigned int)j;
        key = (j == i) ? 0xFFFFFFFFu : key;  // exclude self
#pragma unroll
        for (int s = 0; s < KNN; ++s) {
            const unsigned int lo = min(best[s], key);
            const unsigned int hi = max(best[s], key);
            best[s] = lo;
            key = hi;
        }
    }

#pragma unroll
    for (int s = 0; s < KNN; ++s) lds_keys[seg][pl][s] = best[s];
    for (int st = 1; st < SEGS; st <<= 1) {
        __syncthreads();
        if ((seg & (2 * st - 1)) == 0) {
#pragma unroll
            for (int s = 0; s < KNN; ++s) {
                unsigned int key = lds_keys[seg + st][pl][s];
#pragma unroll
                for (int t = 0; t < KNN; ++t) {
                    const unsigned int lo = min(best[t], key);
                    const unsigned int hi = max(best[t], key);
                    best[t] = lo;
                    key = hi;
                }
            }
#pragma unroll
            for (int s = 0; s < KNN; ++s) lds_keys[seg][pl][s] = best[s];
        }
    }
    if (seg == 0) lds_T[pl] = best[7];  // 8th-smallest of 512 samples
    __syncthreads();
    // round idx bits up so a plain u32 compare on d2_bits equals the masked-key test
    const unsigned int Tp = lds_T[pl] | 0x1FFFu;

    // ---- Phase B: full scan, survivors -> register bitmask (7 VALU/cand) ----
    unsigned int bits[NWORDS];
#pragma unroll
    for (int w = 0; w < NWORDS; ++w) {
        const float4* __restrict__ pw = pts + j0 + w * 32;
        unsigned int m = 0;
#pragma unroll
        for (int c = 0; c < 32; ++c) {
            const float4 q = pw[c];
            const float d2 = fmaxf(fmaf(mx2, q.x, fmaf(my2, q.y, fmaf(mz2, q.z, mp.w + q.w))), 0.0f);
            const unsigned int keep = (__float_as_uint(d2) <= Tp) ? 1u : 0u;
            m = m + m + keep;  // bit (31-c) records candidate c
        }
        bits[w] = m;
    }

    // ---- Phase C: decode survivors, exact key, top-8 insert ----
#pragma unroll
    for (int s = 0; s < KNN; ++s) best[s] = 0xFFFFFFFFu;
#pragma unroll
    for (int w = 0; w < NWORDS; ++w) {
        unsigned int m = bits[w];
        while (m) {
            const int b = __ffs(m) - 1;
            m &= m - 1;               // clear lowest set bit
            const int j = j0 + w * 32 + (31 - b);
            const float4 q = pts[j];
            const float d2 = fmaxf(fmaf(mx2, q.x, fmaf(my2, q.y, fmaf(mz2, q.z, mp.w + q.w))), 0.0f);
            unsigned int key = (__float_as_uint(d2) & 0xFFFFE000u) | (unsigned int)j;
            key = (j == i) ? 0xFFFFFFFFu : key;  // drop self
#pragma unroll
            for (int t = 0; t < KNN; ++t) {
                const unsigned int lo = min(best[t], key);
                const unsigned int hi = max(best[t], key);
                best[t] = lo;
                key = hi;
            }
        }
    }

#pragma unroll
    for (int s = 0; s < KNN; ++s) lds_keys[seg][pl][s] = best[s];
    for (int st = 1; st < SEGS; st <<= 1) {
        __syncthreads();
        if ((seg & (2 * st - 1)) == 0) {
#pragma unroll
            for (int s = 0; s < KNN; ++s) {
                unsigned int key = lds_keys[seg + st][pl][s];
#pragma unroll
                for (int t = 0; t < KNN; ++t) {
                    const unsigned int lo = min(best[t], key);
                    const unsigned int hi = max(best[t], key);
                    best[t] = lo;
                    key = hi;
                }
            }
#pragma unroll
            for (int s = 0; s < KNN; ++s) lds_keys[seg][pl][s] = best[s];
        }
    }
    __syncthreads();
    if (seg == 0) {
#pragma unroll
        for (int s = 0; s < KNN; ++s) lds_nbr[pl][s] = (int)(best[s] & 0x1FFFu);
    }
    __syncthreads();

    // plane distance: one thread per (point, neighbor-rank) for segs 0..7
    float pd = 0.0f;
    if (seg < KNN) {
        const int nbr = lds_nbr[pl][seg];
        const float4 q = pts[nbr];
        const float nx = normals[3 * i + 0];
        const float ny = normals[3 * i + 1];
        const float nz = normals[3 * i + 2];
        pd = fabsf((q.x - mp.x) * nx + (q.y - mp.y) * ny + (q.z - mp.z) * nz);
    }

    // block reduction
    float v = pd;
#pragma unroll
    for (int off = 32; off > 0; off >>= 1) v += __shfl_down(v, off);
    const int wid = tid >> 6;
    if ((tid & 63) == 0) lds_red[wid] = v;
    __syncthreads();
    if (tid == 0) {
        float s = 0.0f;
#pragma unroll
        for (int w = 0; w < BLK / 64; ++w) s += lds_red[w];
        atomicAdd(out, s * (1.0f / ((float)NPTS * (float)KNN)));
    }
}

extern "C" void kernel_launch(void* const* d_in, const int* in_sizes, int n_in,
                              void* d_out, int out_size, void* d_ws, size_t ws_size,
                              hipStream_t stream) {
    const float* means = (const float*)d_in[0];
    const float* normals = (const float*)d_in[1];
    float* out = (float*)d_out;
    float4* pts = (float4*)d_ws;  // 8192 * 16B = 128 KB scratch

    prep_kernel<<<(NPTS + 255) / 256, 256, 0, stream>>>(means, pts, out);
    knn_kernel<<<NPTS / PPB, BLK, 0, stream>>>(pts, normals, out);
}

// Round 8
// 66.305 us; speedup vs baseline: 5.6719x; 5.6719x over previous
//
#include <hip/hip_runtime.h>
#include <hip/hip_bf16.h>

// Problem constants (from setup_inputs): N=8192 points, k=8.
#define NPTS 8192
#define KNN 8
#define SEGS 64                // candidate segments per point -> 32 waves/CU available
#define PPB 8                  // points per block
#define BLK (SEGS * PPB)       // 512 threads, 8 waves
#define SEGLEN (NPTS / SEGS)   // 128 candidates per segment
#define NSAMP 8                // threshold samples per thread (512 per point)
#define NWORDS (SEGLEN / 32)   // 4 bitmask words per thread
// grid = NPTS/PPB = 1024 blocks -> 4 blocks/CU * 8 waves = 32 waves/CU (HW max)
// launch_bounds min-waves=4 (VGPR cap 128): kernel needs ~52 VGPR <= 64, so HW
// still grants 8 waves/SIMD. R7's min-waves=8 capped VGPR at 32 -> 1.9 GB of
// scratch spill traffic per dispatch. Never cap below the live set.

// Pack (x,y,z,|p|^2) and zero the output accumulator.
__global__ __launch_bounds__(256) void prep_kernel(const float* __restrict__ means,
                                                   float4* __restrict__ pts,
                                                   float* __restrict__ out) {
    int i = blockIdx.x * 256 + threadIdx.x;
    if (i == 0 && blockIdx.x == 0) out[0] = 0.0f;
    if (i < NPTS) {
        float x = means[3 * i + 0];
        float y = means[3 * i + 1];
        float z = means[3 * i + 2];
        pts[i] = make_float4(x, y, z, x * x + y * y + z * z);
    }
}

// Exact kNN via sample-threshold filter with register-bitmask survivors:
//  A) 512 sampled candidates/point -> T = 8th-smallest sampled key (upper bound
//     on the true 8th key, since the sample is a subset).
//  B) full scan; keep-bit per candidate: m = m+m+keep (2 VALU). ~7 VALU/cand
//     total; no LDS traffic, no capacity limit.
//  C) decode set bits (~2/thread), recompute exact f32 d2, insert-8 + tree merge.
// Keys pack (d2 top 19 bits | 13-bit idx): unique, total order, jax tie-break.
__global__ __launch_bounds__(BLK, 4) void knn_kernel(const float4* __restrict__ pts,
                                                     const float* __restrict__ normals,
                                                     float* __restrict__ out) {
    __shared__ unsigned int lds_keys[SEGS][PPB][KNN + 1];  // merge scratch (+1 pad)
    __shared__ unsigned int lds_T[PPB];
    __shared__ int lds_nbr[PPB][KNN];
    __shared__ float lds_red[BLK / 64];

    const int tid = threadIdx.x;
    const int pl = tid & (PPB - 1);   // point within block
    const int seg = tid >> 3;         // segment (PPB==8)
    const int i = blockIdx.x * PPB + pl;

    const float4 mp = pts[i];
    const float mx2 = -2.0f * mp.x;
    const float my2 = -2.0f * mp.y;
    const float mz2 = -2.0f * mp.z;
    const int j0 = seg * SEGLEN;

    unsigned int best[KNN];
#pragma unroll
    for (int s = 0; s < KNN; ++s) best[s] = 0xFFFFFFFFu;

    // ---- Phase A: sampled scan with full insert (8 samples, stride 16) ----
#pragma unroll
    for (int s8 = 0; s8 < NSAMP; ++s8) {
        const int j = j0 + s8 * (SEGLEN / NSAMP);
        const float4 q = pts[j];
        const float d2 = fmaxf(fmaf(mx2, q.x, fmaf(my2, q.y, fmaf(mz2, q.z, mp.w + q.w))), 0.0f);
        unsigned int key = (__float_as_uint(d2) & 0xFFFFE000u) | (unsigned int)j;
        key = (j == i) ? 0xFFFFFFFFu : key;  // exclude self
#pragma unroll
        for (int s = 0; s < KNN; ++s) {
            const unsigned int lo = min(best[s], key);
            const unsigned int hi = max(best[s], key);
            best[s] = lo;
            key = hi;
        }
    }

#pragma unroll
    for (int s = 0; s < KNN; ++s) lds_keys[seg][pl][s] = best[s];
    for (int st = 1; st < SEGS; st <<= 1) {
        __syncthreads();
        if ((seg & (2 * st - 1)) == 0) {
#pragma unroll
            for (int s = 0; s < KNN; ++s) {
                unsigned int key = lds_keys[seg + st][pl][s];
#pragma unroll
                for (int t = 0; t < KNN; ++t) {
                    const unsigned int lo = min(best[t], key);
                    const unsigned int hi = max(best[t], key);
                    best[t] = lo;
                    key = hi;
                }
            }
#pragma unroll
            for (int s = 0; s < KNN; ++s) lds_keys[seg][pl][s] = best[s];
        }
    }
    if (seg == 0) lds_T[pl] = best[7];  // 8th-smallest of 512 samples
    __syncthreads();
    // round idx bits up so a plain u32 compare on d2_bits equals the masked-key test
    const unsigned int Tp = lds_T[pl] | 0x1FFFu;

    // ---- Phase B: full scan, survivors -> register bitmask ----
    unsigned int bits[NWORDS];
    for (int w = 0; w < NWORDS; ++w) {
        const float4* __restrict__ pw = pts + j0 + w * 32;
        unsigned int m = 0;
#pragma unroll
        for (int c = 0; c < 32; ++c) {
            const float4 q = pw[c];
            const float d2 = fmaxf(fmaf(mx2, q.x, fmaf(my2, q.y, fmaf(mz2, q.z, mp.w + q.w))), 0.0f);
            const unsigned int keep = (__float_as_uint(d2) <= Tp) ? 1u : 0u;
            m = m + m + keep;  // bit (31-c) records candidate c
        }
        bits[w] = m;
    }

    // ---- Phase C: decode survivors, exact key, top-8 insert ----
#pragma unroll
    for (int s = 0; s < KNN; ++s) best[s] = 0xFFFFFFFFu;
    for (int w = 0; w < NWORDS; ++w) {
        unsigned int m = bits[w];
        while (m) {
            const int b = __ffs(m) - 1;
            m &= m - 1;               // clear lowest set bit
            const int j = j0 + w * 32 + (31 - b);
            const float4 q = pts[j];
            const float d2 = fmaxf(fmaf(mx2, q.x, fmaf(my2, q.y, fmaf(mz2, q.z, mp.w + q.w))), 0.0f);
            unsigned int key = (__float_as_uint(d2) & 0xFFFFE000u) | (unsigned int)j;
            key = (j == i) ? 0xFFFFFFFFu : key;  // drop self
#pragma unroll
            for (int t = 0; t < KNN; ++t) {
                const unsigned int lo = min(best[t], key);
                const unsigned int hi = max(best[t], key);
                best[t] = lo;
                key = hi;
            }
        }
    }

#pragma unroll
    for (int s = 0; s < KNN; ++s) lds_keys[seg][pl][s] = best[s];
    for (int st = 1; st < SEGS; st <<= 1) {
        __syncthreads();
        if ((seg & (2 * st - 1)) == 0) {
#pragma unroll
            for (int s = 0; s < KNN; ++s) {
                unsigned int key = lds_keys[seg + st][pl][s];
#pragma unroll
                for (int t = 0; t < KNN; ++t) {
                    const unsigned int lo = min(best[t], key);
                    const unsigned int hi = max(best[t], key);
                    best[t] = lo;
                    key = hi;
                }
            }
#pragma unroll
            for (int s = 0; s < KNN; ++s) lds_keys[seg][pl][s] = best[s];
        }
    }
    __syncthreads();
    if (seg == 0) {
#pragma unroll
        for (int s = 0; s < KNN; ++s) lds_nbr[pl][s] = (int)(best[s] & 0x1FFFu);
    }
    __syncthreads();

    // plane distance: one thread per (point, neighbor-rank) for segs 0..7
    float pd = 0.0f;
    if (seg < KNN) {
        const int nbr = lds_nbr[pl][seg];
        const float4 q = pts[nbr];
        const float nx = normals[3 * i + 0];
        const float ny = normals[3 * i + 1];
        const float nz = normals[3 * i + 2];
        pd = fabsf((q.x - mp.x) * nx + (q.y - mp.y) * ny + (q.z - mp.z) * nz);
    }

    // block reduction
    float v = pd;
#pragma unroll
    for (int off = 32; off > 0; off >>= 1) v += __shfl_down(v, off);
    const int wid = tid >> 6;
    if ((tid & 63) == 0) lds_red[wid] = v;
    __syncthreads();
    if (tid == 0) {
        float s = 0.0f;
#pragma unroll
        for (int w = 0; w < BLK / 64; ++w) s += lds_red[w];
        atomicAdd(out, s * (1.0f / ((float)NPTS * (float)KNN)));
    }
}

extern "C" void kernel_launch(void* const* d_in, const int* in_sizes, int n_in,
                              void* d_out, int out_size, void* d_ws, size_t ws_size,
                              hipStream_t stream) {
    const float* means = (const float*)d_in[0];
    const float* normals = (const float*)d_in[1];
    float* out = (float*)d_out;
    float4* pts = (float4*)d_ws;  // 8192 * 16B = 128 KB scratch

    prep_kernel<<<(NPTS + 255) / 256, 256, 0, stream>>>(means, pts, out);
    knn_kernel<<<NPTS / PPB, BLK, 0, stream>>>(pts, normals, out);
}

// Round 9
// 59.162 us; speedup vs baseline: 6.3566x; 1.1207x over previous
//
#include <hip/hip_runtime.h>
#include <hip/hip_bf16.h>

// Problem: N=8192 points, k=8 exact kNN -> mean |plane distance|.
// Parallelization (R9): lane = point, wave = candidate slice. All 64 lanes
// scan the SAME candidate per iteration -> wave-uniform address (forced via
// readfirstlane) -> scalar loads, ONE 16B L2 request per candidate per wave
// instead of 64. Kills the 1.07 GB / ~31 us L2-bandwidth wall of R1-R8.
#define NPTS 8192
#define KNN 8
#define NB 4                    // candidate-slice blocks per 64-point group
#define WAVES 8                 // waves per block
#define BLK (WAVES * 64)        // 512 threads
#define SLICE (NPTS / NB)       // 2048 candidates per block
#define WSLICE (SLICE / WAVES)  // 256 candidates per wave
#define NWORDS (WSLICE / 32)    // 8 bitmask words
#define SSTR 8                  // sample stride -> 32 samples/wave, 256/point
#define NSAMP (WSLICE / SSTR)
// grid1 = (NPTS/64)*NB = 512 blocks -> 2 blocks/CU, 16 waves/CU.
// ws: float4 pts[8192] (128KB) + u32 part[512][64][8] (1MB).

__device__ __forceinline__ void insert8(unsigned int (&best)[KNN], unsigned int key) {
#pragma unroll
    for (int t = 0; t < KNN; ++t) {
        const unsigned int lo = min(best[t], key);
        key = max(best[t], key);
        best[t] = lo;
    }
}

// Pack (x,y,z,|p|^2) and zero the output accumulator.
__global__ __launch_bounds__(256) void prep_kernel(const float* __restrict__ means,
                                                   float4* __restrict__ pts,
                                                   float* __restrict__ out) {
    int i = blockIdx.x * 256 + threadIdx.x;
    if (i == 0 && blockIdx.x == 0) out[0] = 0.0f;
    if (i < NPTS) {
        float x = means[3 * i + 0];
        float y = means[3 * i + 1];
        float z = means[3 * i + 2];
        pts[i] = make_float4(x, y, z, x * x + y * y + z * z);
    }
}

// Per-block: 64 points (one per lane), candidate slice of 2048 (256 per wave).
//  A) 256 sampled candidates/point -> T = 8th-smallest sampled key (>= true 8th
//     of the slice, since sample subset of slice; >= slice 8th >= global 8th).
//  B) scan wave slice; keep-bit -> register bitmask (7 VALU/cand, scalar loads).
//  C) decode survivors (~8/lane), exact clamped key, insert-8; LDS tree-merge
//     across 8 waves; write block-partial top-8 per point to ws.
// Keys pack (clamped d2 top 19 bits | 13-bit idx): unique, jax tie-break.
__global__ __launch_bounds__(BLK) void knn_part(const float4* __restrict__ pts,
                                                unsigned int* __restrict__ part) {
    __shared__ unsigned int lds_keys[WAVES][64][KNN + 1];  // +1 pad: conflict-free
    __shared__ unsigned int lds_T[64];

    const int tid = threadIdx.x;
    const int lane = tid & 63;
    const int wv = tid >> 6;
    const int g = blockIdx.x >> 2;        // point group (NB==4)
    const int bs = blockIdx.x & 3;        // slice index within group
    const int i = g * 64 + lane;          // this lane's point

    const int ubase = __builtin_amdgcn_readfirstlane(bs * SLICE + wv * WSLICE);
    const float4* __restrict__ pw = pts + ubase;  // uniform base -> scalar loads

    const float4 mp = pts[i];
    const float mx2 = -2.0f * mp.x;
    const float my2 = -2.0f * mp.y;
    const float mz2 = -2.0f * mp.z;

    unsigned int best[KNN];
#pragma unroll
    for (int s = 0; s < KNN; ++s) best[s] = 0xFFFFFFFFu;

    // ---- Phase A: sampled scan (32 uniform samples) with full insert ----
#pragma unroll 8
    for (int s8 = 0; s8 < NSAMP; ++s8) {
        const int c = s8 * SSTR;
        const float4 q = pw[c];
        const float d2 = fmaxf(fmaf(mx2, q.x, fmaf(my2, q.y, fmaf(mz2, q.z, mp.w + q.w))), 0.0f);
        const int j = ubase + c;
        unsigned int key = (__float_as_uint(d2) & 0xFFFFE000u) | (unsigned int)j;
        key = (j == i) ? 0xFFFFFFFFu : key;  // exclude self
        insert8(best, key);
    }

    // cross-wave tree merge of sampled top-8 (lanes parallel over 64 points)
#pragma unroll
    for (int s = 0; s < KNN; ++s) lds_keys[wv][lane][s] = best[s];
    for (int st = 1; st < WAVES; st <<= 1) {
        __syncthreads();
        if ((wv & (2 * st - 1)) == 0) {
#pragma unroll
            for (int s = 0; s < KNN; ++s) insert8(best, lds_keys[wv + st][lane][s]);
#pragma unroll
            for (int s = 0; s < KNN; ++s) lds_keys[wv][lane][s] = best[s];
        }
    }
    if (wv == 0) lds_T[lane] = best[7] | 0x1FFFu;  // idx bits rounded up
    __syncthreads();
    const unsigned int Tp = lds_T[lane];

    // ---- Phase B: scan wave slice, survivors -> register bitmask ----
    unsigned int bits[NWORDS];
#pragma unroll
    for (int w = 0; w < NWORDS; ++w) {
        const float4* __restrict__ qw = pw + w * 32;
        unsigned int m = 0;
#pragma unroll
        for (int c = 0; c < 32; ++c) {
            const float4 q = qw[c];
            const float d2 = fmaxf(fmaf(mx2, q.x, fmaf(my2, q.y, fmaf(mz2, q.z, mp.w + q.w))), 0.0f);
            m = m + m + ((__float_as_uint(d2) <= Tp) ? 1u : 0u);  // bit (31-c)
        }
        bits[w] = m;
    }

    // ---- Phase C: decode survivors (~8/lane), exact key, top-8 insert ----
#pragma unroll
    for (int s = 0; s < KNN; ++s) best[s] = 0xFFFFFFFFu;
#pragma unroll
    for (int w = 0; w < NWORDS; ++w) {
        unsigned int m = bits[w];
        while (m) {
            const int b = __ffs(m) - 1;
            m &= m - 1;
            const int c = w * 32 + (31 - b);   // per-lane divergent -> vector load
            const float4 q = pw[c];
            const float d2 = fmaxf(fmaf(mx2, q.x, fmaf(my2, q.y, fmaf(mz2, q.z, mp.w + q.w))), 0.0f);
            const int j = ubase + c;
            unsigned int key = (__float_as_uint(d2) & 0xFFFFE000u) | (unsigned int)j;
            key = (j == i) ? 0xFFFFFFFFu : key;  // drop self
            insert8(best, key);
        }
    }

    // cross-wave tree merge of slice top-8
#pragma unroll
    for (int s = 0; s < KNN; ++s) lds_keys[wv][lane][s] = best[s];
    for (int st = 1; st < WAVES; st <<= 1) {
        __syncthreads();
        if ((wv & (2 * st - 1)) == 0) {
#pragma unroll
            for (int s = 0; s < KNN; ++s) insert8(best, lds_keys[wv + st][lane][s]);
#pragma unroll
            for (int s = 0; s < KNN; ++s) lds_keys[wv][lane][s] = best[s];
        }
    }
    if (wv == 0) {
        unsigned int* dst = part + (((unsigned int)blockIdx.x * 64u + (unsigned int)lane) * 8u);
        *reinterpret_cast<uint4*>(dst) = make_uint4(best[0], best[1], best[2], best[3]);
        *reinterpret_cast<uint4*>(dst + 4) = make_uint4(best[4], best[5], best[6], best[7]);
    }
}

// Merge NB block-partials per point (32 keys -> exact top-8), plane distance,
// block reduce, one atomic per block.
__global__ __launch_bounds__(256) void knn_final(const float4* __restrict__ pts,
                                                 const float* __restrict__ normals,
                                                 const unsigned int* __restrict__ part,
                                                 float* __restrict__ out) {
    __shared__ float lds_red[4];
    const int t = blockIdx.x * 256 + threadIdx.x;
    const int g = t >> 6;
    const int pt = t & 63;

    unsigned int best[KNN];
#pragma unroll
    for (int s = 0; s < KNN; ++s) best[s] = 0xFFFFFFFFu;
#pragma unroll
    for (int b = 0; b < NB; ++b) {
        const unsigned int* L = part + ((((unsigned int)(g * NB + b)) * 64u + (unsigned int)pt) * 8u);
        const uint4 a = *reinterpret_cast<const uint4*>(L);
        const uint4 c = *reinterpret_cast<const uint4*>(L + 4);
        insert8(best, a.x); insert8(best, a.y); insert8(best, a.z); insert8(best, a.w);
        insert8(best, c.x); insert8(best, c.y); insert8(best, c.z); insert8(best, c.w);
    }

    const float4 mp = pts[t];
    const float nx = normals[3 * t + 0];
    const float ny = normals[3 * t + 1];
    const float nz = normals[3 * t + 2];
    float sum = 0.0f;
#pragma unroll
    for (int s = 0; s < KNN; ++s) {
        const int nbr = (int)(best[s] & 0x1FFFu);
        const float4 q = pts[nbr];
        sum += fabsf((q.x - mp.x) * nx + (q.y - mp.y) * ny + (q.z - mp.z) * nz);
    }

    float v = sum;
#pragma unroll
    for (int off = 32; off > 0; off >>= 1) v += __shfl_down(v, off);
    if ((threadIdx.x & 63) == 0) lds_red[threadIdx.x >> 6] = v;
    __syncthreads();
    if (threadIdx.x == 0) {
        atomicAdd(out, (lds_red[0] + lds_red[1] + lds_red[2] + lds_red[3]) *
                           (1.0f / ((float)NPTS * (float)KNN)));
    }
}

extern "C" void kernel_launch(void* const* d_in, const int* in_sizes, int n_in,
                              void* d_out, int out_size, void* d_ws, size_t ws_size,
                              hipStream_t stream) {
    const float* means = (const float*)d_in[0];
    const float* normals = (const float*)d_in[1];
    float* out = (float*)d_out;
    float4* pts = (float4*)d_ws;                                  // 128 KB
    unsigned int* part = (unsigned int*)((char*)d_ws + NPTS * 16); // 1 MB

    prep_kernel<<<NPTS / 256, 256, 0, stream>>>(means, pts, out);
    knn_part<<<(NPTS / 64) * NB, BLK, 0, stream>>>(pts, part);
    knn_final<<<NPTS / 256, 256, 0, stream>>>(pts, normals, part, out);
}